// Round 2
// baseline (210.757 us; speedup 1.0000x reference)
//
#include <hip/hip_runtime.h>
#include <math.h>

#define TPB 256          // threads per block
#define SPT 2            // samples per thread
#define SPB (TPB * SPT)  // samples per block

// HW-approx rcp/sqrt (v_rcp_f32 / v_sqrt_f32, ~1e-6 rel err). Error budget:
// sigma3 needs only ~0.4% rel accuracy once det is exact (fp64), and the
// final sv^-2 terms tolerate 1e-6 rel against the absmax-scaled threshold.
__device__ __forceinline__ float fast_rcp(float x)  { return __builtin_amdgcn_rcpf(x); }
__device__ __forceinline__ float fast_sqrt(float x) { return __builtin_amdgcn_sqrtf(x); }

// Ortho term for one sample. fp32 throughout EXCEPT detW (fp64): det has
// catastrophic cancellation (true value ~sigma1*sigma2*sigma3 << term
// magnitudes) and sigma_min feeds (sigma+eps)^-2 ~ 1e12 which dominates the
// loss.
__device__ __forceinline__ void sample_ortho(const float4 t0, const float4 t1,
                                             const float4 t2, double& ortho)
{
    float w00 = t0.x, w01 = t0.y, w02 = t0.z;
    float w10 = t1.x, w11 = t1.y, w12 = t1.z;
    float w20 = t2.x, w21 = t2.y, w22 = t2.z;

    // A = W^T W (fp32)
    float A00 = w00*w00 + w10*w10 + w20*w20;
    float A11 = w01*w01 + w11*w11 + w21*w21;
    float A22 = w02*w02 + w12*w12 + w22*w22;
    float A01 = w00*w01 + w10*w11 + w20*w21;
    float A02 = w00*w02 + w10*w12 + w20*w22;
    float A12 = w01*w02 + w11*w12 + w21*w22;

    float I1 = A00 + A11 + A22;
    float I2 = (A00*A11 - A01*A01) + (A00*A22 - A02*A02) + (A11*A22 - A12*A12);

    // det(W) in fp64 — the one cancellation-critical quantity.
    double dw = (double)w00 * ((double)w11 * (double)w22 - (double)w12 * (double)w21)
              - (double)w01 * ((double)w10 * (double)w22 - (double)w12 * (double)w20)
              + (double)w02 * ((double)w10 * (double)w21 - (double)w11 * (double)w20);
    float I3 = (float)(dw * dw);   // det(A) >= 0

    // Smallest eigenvalue: monotone fixed point lam <- I3 / q(lam),
    // q(lam) = lam^2 - I1*lam + I2. Converges from below; immediate for the
    // near-singular samples that dominate the loss.
    float lam = (I2 > 0.f) ? I3 * fast_rcp(I2) : 0.f;
    #pragma unroll
    for (int it = 0; it < 6; ++it) {
        float q = (lam - I1) * lam + I2;
        lam = (q > 0.f) ? I3 * fast_rcp(q) : lam;
    }
    if (lam < 0.f) lam = 0.f;

    // Remaining two eigenvalues from the deflated quadratic.
    float S = I1 - lam;
    float P = (lam - I1) * lam + I2;    // ~ lam1*lam2
    float disc = S * S - 4.f * P;
    disc = (disc > 0.f) ? fast_sqrt(disc) : 0.f;
    float l1 = 0.5f * (S + disc); if (l1 < 0.f) l1 = 0.f;
    float l2 = 0.5f * (S - disc); if (l2 < 0.f) l2 = 0.f;

    float s1 = fast_sqrt(l1)  + 1e-6f;
    float s2 = fast_sqrt(l2)  + 1e-6f;
    float s3 = fast_sqrt(lam) + 1e-6f;
    float q1 = s1 * s1, q2 = s2 * s2, q3 = s3 * s3;
    float inv = fast_rcp(q1 * q2 * q3);
    ortho += (double)((q1 + q2 + q3) + inv * (q2 * q3 + q1 * q3 + q1 * q2) - 6.f);
}

// Single fused kernel: direct strided loads (no LDS staging — every byte is
// consumed exactly once, L1 merges the 48B-stride line touches), per-block
// reduce, fp64 device-scope atomicAdd into ws accumulators, last-block-done
// ticket writes the final output. Removes the finalize dispatch + its gap.
__global__ __launch_bounds__(256) void theta_loss_fused(
    const float4* __restrict__ theta4,
    const float4* __restrict__ affine4,
    double* __restrict__ acc,          // acc[0]=ortho, acc[1]=mse (pre-zeroed)
    unsigned int* __restrict__ ticket, // pre-zeroed
    float* __restrict__ out,
    int n, int nblocks)
{
    const int t = threadIdx.x;
    const int base = blockIdx.x * SPB + t;   // k-th sample: base + k*TPB
    double mse = 0.0, ortho = 0.0;

    float4 tv[SPT][3], av[SPT][3];
    #pragma unroll
    for (int k = 0; k < SPT; ++k) {
        int s = base + k * TPB;
        if (s < n) {
            int j = 3 * s;
            tv[k][0] = theta4[j];     tv[k][1] = theta4[j + 1];  tv[k][2] = theta4[j + 2];
            av[k][0] = affine4[j];    av[k][1] = affine4[j + 1]; av[k][2] = affine4[j + 2];
        } else {
            #pragma unroll
            for (int r = 0; r < 3; ++r) {
                tv[k][r] = make_float4(0.f, 0.f, 0.f, 0.f);
                av[k][r] = make_float4(0.f, 0.f, 0.f, 0.f);
            }
        }
    }

    // MSE: fp32 within a sample (<= 12 squared diffs), widen once.
    #pragma unroll
    for (int k = 0; k < SPT; ++k) {
        float m = 0.f;
        #pragma unroll
        for (int r = 0; r < 3; ++r) {
            float dx = tv[k][r].x - av[k][r].x, dy = tv[k][r].y - av[k][r].y;
            float dz = tv[k][r].z - av[k][r].z, dw = tv[k][r].w - av[k][r].w;
            m += dx * dx + dy * dy + dz * dz + dw * dw;
        }
        mse += (double)m;
    }

    #pragma unroll
    for (int k = 0; k < SPT; ++k) {
        if (base + k * TPB < n)
            sample_ortho(tv[k][0], tv[k][1], tv[k][2], ortho);
    }

    // ---- block reduction: wave64 shuffle -> LDS -> thread 0 ----
    #pragma unroll
    for (int off = 32; off > 0; off >>= 1) {
        ortho += __shfl_down(ortho, off);
        mse   += __shfl_down(mse, off);
    }
    __shared__ double so[4], sm[4];
    int lane = t & 63, wv = t >> 6;
    if (lane == 0) { so[wv] = ortho; sm[wv] = mse; }
    __syncthreads();

    if (t == 0) {
        double bo = so[0] + so[1] + so[2] + so[3];
        double bm = sm[0] + sm[1] + sm[2] + sm[3];
        // Device-scope fp64 atomics (global_atomic_add_f64); 2048 blocks,
        // negligible contention. Reorder error ~1e-12 rel.
        atomicAdd(&acc[0], bo);
        atomicAdd(&acc[1], bm);
        __threadfence();                       // make adds visible device-wide
        unsigned int old = atomicAdd(ticket, 1u);
        if (old == (unsigned int)nblocks - 1u) {
            // fetch-add(0): coherent read at the same coherence point that
            // serialized all prior adds (safe across XCD L2s).
            double Ot = atomicAdd(&acc[0], 0.0);
            double Mt = atomicAdd(&acc[1], 0.0);
            out[0] = (float)(Ot / (double)n);
            out[1] = (float)(Mt / (12.0 * (double)n));
        }
    }
}

extern "C" void kernel_launch(void* const* d_in, const int* in_sizes, int n_in,
                              void* d_out, int out_size, void* d_ws, size_t ws_size,
                              hipStream_t stream) {
    const float4* theta4  = (const float4*)d_in[0];
    const float4* affine4 = (const float4*)d_in[1];
    double* acc = (double*)d_ws;                               // 2 doubles
    unsigned int* ticket = (unsigned int*)((char*)d_ws + 16);  // 1 uint
    float* out = (float*)d_out;
    int n = in_sizes[0] / 12;           // samples of 3x4

    int blocks = (n + SPB - 1) / SPB;   // 2048 for n = 1M
    // Zero the accumulators + ticket (workspace is poisoned by the harness).
    // Stream-ordered, graph-capturable.
    hipMemsetAsync(d_ws, 0, 24, stream);
    theta_loss_fused<<<blocks, TPB, 0, stream>>>(theta4, affine4, acc, ticket,
                                                 out, n, blocks);
}

// Round 3
// 127.834 us; speedup vs baseline: 1.6487x; 1.6487x over previous
//
#include <hip/hip_runtime.h>
#include <math.h>

#define TPB 256          // threads per block
#define SPT 2            // samples per thread
#define SPB (TPB * SPT)  // samples per block

// HW-approx rcp/sqrt (v_rcp_f32 / v_sqrt_f32, ~1e-6 rel err). Error budget:
// sigma3 needs only ~0.4% rel accuracy once det is exact (fp64), and the
// final sv^-2 terms tolerate 1e-6 rel against the absmax-scaled threshold.
__device__ __forceinline__ float fast_rcp(float x)  { return __builtin_amdgcn_rcpf(x); }
__device__ __forceinline__ float fast_sqrt(float x) { return __builtin_amdgcn_sqrtf(x); }

// Ortho term for one sample. fp32 throughout EXCEPT detW (fp64): det has
// catastrophic cancellation (true value ~sigma1*sigma2*sigma3 << term
// magnitudes) and sigma_min feeds (sigma+eps)^-2 ~ 1e12 which dominates the
// loss.
__device__ __forceinline__ void sample_ortho(const float4 t0, const float4 t1,
                                             const float4 t2, double& ortho)
{
    float w00 = t0.x, w01 = t0.y, w02 = t0.z;
    float w10 = t1.x, w11 = t1.y, w12 = t1.z;
    float w20 = t2.x, w21 = t2.y, w22 = t2.z;

    // A = W^T W (fp32)
    float A00 = w00*w00 + w10*w10 + w20*w20;
    float A11 = w01*w01 + w11*w11 + w21*w21;
    float A22 = w02*w02 + w12*w12 + w22*w22;
    float A01 = w00*w01 + w10*w11 + w20*w21;
    float A02 = w00*w02 + w10*w12 + w20*w22;
    float A12 = w01*w02 + w11*w12 + w21*w22;

    float I1 = A00 + A11 + A22;
    float I2 = (A00*A11 - A01*A01) + (A00*A22 - A02*A02) + (A11*A22 - A12*A12);

    // det(W) in fp64 — the one cancellation-critical quantity.
    double dw = (double)w00 * ((double)w11 * (double)w22 - (double)w12 * (double)w21)
              - (double)w01 * ((double)w10 * (double)w22 - (double)w12 * (double)w20)
              + (double)w02 * ((double)w10 * (double)w21 - (double)w11 * (double)w20);
    float I3 = (float)(dw * dw);   // det(A) >= 0

    // Smallest eigenvalue: monotone fixed point lam <- I3 / q(lam),
    // q(lam) = lam^2 - I1*lam + I2. Converges from below; immediate for the
    // near-singular samples that dominate the loss.
    float lam = (I2 > 0.f) ? I3 * fast_rcp(I2) : 0.f;
    #pragma unroll
    for (int it = 0; it < 6; ++it) {
        float q = (lam - I1) * lam + I2;
        lam = (q > 0.f) ? I3 * fast_rcp(q) : lam;
    }
    if (lam < 0.f) lam = 0.f;

    // Remaining two eigenvalues from the deflated quadratic.
    float S = I1 - lam;
    float P = (lam - I1) * lam + I2;    // ~ lam1*lam2
    float disc = S * S - 4.f * P;
    disc = (disc > 0.f) ? fast_sqrt(disc) : 0.f;
    float l1 = 0.5f * (S + disc); if (l1 < 0.f) l1 = 0.f;
    float l2 = 0.5f * (S - disc); if (l2 < 0.f) l2 = 0.f;

    float s1 = fast_sqrt(l1)  + 1e-6f;
    float s2 = fast_sqrt(l2)  + 1e-6f;
    float s3 = fast_sqrt(lam) + 1e-6f;
    float q1 = s1 * s1, q2 = s2 * s2, q3 = s3 * s3;
    float inv = fast_rcp(q1 * q2 * q3);
    ortho += (double)((q1 + q2 + q3) + inv * (q2 * q3 + q1 * q3 + q1 * q2) - 6.f);
}

// Fused single-dispatch kernel. Epilogue design (post-mortem of the
// __threadfence() disaster: device-scope fence = buffer_wbl2 per block,
// 2048 L2 flushes serialized the tail at ~100us):
//   - per-block partials via RELAXED AGENT atomic stores (global_store sc1:
//     write-through to the coherence point, NO L2 flush, fully pipelined)
//   - hand-rolled release: s_waitcnt vmcnt(0) -- the official gfx94x
//     release sequence minus buffer_wbl2, valid because every prior
//     communicating write is itself an sc1 store
//   - ONE relaxed agent ticket RMW per block (memory-side atomic, pipelined)
//   - last block re-reads partials with relaxed agent atomic loads (sc1
//     bypasses any stale L1/L2) and writes out[] directly.
__global__ __launch_bounds__(256) void theta_loss_fused(
    const float4* __restrict__ theta4,
    const float4* __restrict__ affine4,
    unsigned int* __restrict__ ticket,  // ws+0, pre-zeroed via memset
    double* __restrict__ partial,       // ws+16, 2 doubles per block
    float* __restrict__ out,
    int n, int nblocks)
{
    const int t = threadIdx.x;
    const int base = blockIdx.x * SPB + t;   // k-th sample: base + k*TPB
    double mse = 0.0, ortho = 0.0;

    float4 tv[SPT][3], av[SPT][3];
    #pragma unroll
    for (int k = 0; k < SPT; ++k) {
        int s = base + k * TPB;
        if (s < n) {
            int j = 3 * s;
            tv[k][0] = theta4[j];     tv[k][1] = theta4[j + 1];  tv[k][2] = theta4[j + 2];
            av[k][0] = affine4[j];    av[k][1] = affine4[j + 1]; av[k][2] = affine4[j + 2];
        } else {
            #pragma unroll
            for (int r = 0; r < 3; ++r) {
                tv[k][r] = make_float4(0.f, 0.f, 0.f, 0.f);
                av[k][r] = make_float4(0.f, 0.f, 0.f, 0.f);
            }
        }
    }

    // MSE: fp32 within a sample (<= 12 squared diffs), widen once.
    #pragma unroll
    for (int k = 0; k < SPT; ++k) {
        float m = 0.f;
        #pragma unroll
        for (int r = 0; r < 3; ++r) {
            float dx = tv[k][r].x - av[k][r].x, dy = tv[k][r].y - av[k][r].y;
            float dz = tv[k][r].z - av[k][r].z, dw = tv[k][r].w - av[k][r].w;
            m += dx * dx + dy * dy + dz * dz + dw * dw;
        }
        mse += (double)m;
    }

    #pragma unroll
    for (int k = 0; k < SPT; ++k) {
        if (base + k * TPB < n)
            sample_ortho(tv[k][0], tv[k][1], tv[k][2], ortho);
    }

    // ---- block reduction: wave64 shuffle -> LDS -> thread 0 ----
    #pragma unroll
    for (int off = 32; off > 0; off >>= 1) {
        ortho += __shfl_down(ortho, off);
        mse   += __shfl_down(mse, off);
    }
    __shared__ double so[4], sm[4];
    __shared__ int lastFlag;
    int lane = t & 63, wv = t >> 6;
    if (lane == 0) { so[wv] = ortho; sm[wv] = mse; }
    __syncthreads();

    if (t == 0) {
        double bo = so[0] + so[1] + so[2] + so[3];
        double bm = sm[0] + sm[1] + sm[2] + sm[3];
        // sc1 write-through stores: visible at the device coherence point,
        // no cache flush involved.
        __hip_atomic_store(&partial[2 * blockIdx.x],     bo,
                           __ATOMIC_RELAXED, __HIP_MEMORY_SCOPE_AGENT);
        __hip_atomic_store(&partial[2 * blockIdx.x + 1], bm,
                           __ATOMIC_RELAXED, __HIP_MEMORY_SCOPE_AGENT);
        // Hand-rolled release: wait until both sc1 stores have reached the
        // coherence point, then publish via the ticket. No buffer_wbl2.
        asm volatile("s_waitcnt vmcnt(0)" ::: "memory");
        unsigned int old = __hip_atomic_fetch_add(ticket, 1u,
                           __ATOMIC_RELAXED, __HIP_MEMORY_SCOPE_AGENT);
        lastFlag = (old == (unsigned int)(nblocks - 1)) ? 1 : 0;
    }
    __syncthreads();

    if (lastFlag) {
        // Last block: gather all partials with sc1 loads (bypass stale
        // caches) and reduce across the block.
        double O = 0.0, M = 0.0;
        for (int i = t; i < nblocks; i += TPB) {
            O += __hip_atomic_load(&partial[2 * i],
                                   __ATOMIC_RELAXED, __HIP_MEMORY_SCOPE_AGENT);
            M += __hip_atomic_load(&partial[2 * i + 1],
                                   __ATOMIC_RELAXED, __HIP_MEMORY_SCOPE_AGENT);
        }
        #pragma unroll
        for (int off = 32; off > 0; off >>= 1) {
            O += __shfl_down(O, off);
            M += __shfl_down(M, off);
        }
        __syncthreads();               // reuse so/sm safely
        if (lane == 0) { so[wv] = O; sm[wv] = M; }
        __syncthreads();
        if (t == 0) {
            double Ot = so[0] + so[1] + so[2] + so[3];
            double Mt = sm[0] + sm[1] + sm[2] + sm[3];
            out[0] = (float)(Ot / (double)n);
            out[1] = (float)(Mt / (12.0 * (double)n));
        }
    }
}

extern "C" void kernel_launch(void* const* d_in, const int* in_sizes, int n_in,
                              void* d_out, int out_size, void* d_ws, size_t ws_size,
                              hipStream_t stream) {
    const float4* theta4  = (const float4*)d_in[0];
    const float4* affine4 = (const float4*)d_in[1];
    unsigned int* ticket = (unsigned int*)d_ws;            // ws+0
    double* partial = (double*)((char*)d_ws + 16);         // ws+16
    float* out = (float*)d_out;
    int n = in_sizes[0] / 12;           // samples of 3x4

    int blocks = (n + SPB - 1) / SPB;   // 2048 for n = 1M
    // Zero only the ticket word (workspace is poisoned by the harness).
    hipMemsetAsync(d_ws, 0, 16, stream);
    theta_loss_fused<<<blocks, TPB, 0, stream>>>(theta4, affine4, ticket,
                                                 partial, out, n, blocks);
}

// Round 4
// 117.833 us; speedup vs baseline: 1.7886x; 1.0849x over previous
//
#include <hip/hip_runtime.h>
#include <math.h>

#define TPB 256          // threads per block
#define SPT 4            // samples per thread
#define SPB (TPB * SPT)  // samples per block

// HW-approx rcp/sqrt (v_rcp_f32 / v_sqrt_f32, ~1e-6 rel err). Error budget:
// sigma3 needs only ~0.4% rel accuracy once det is exact (fp64), and the
// final sv^-2 terms tolerate 1e-6 rel against the absmax-scaled threshold.
__device__ __forceinline__ float fast_rcp(float x)  { return __builtin_amdgcn_rcpf(x); }
__device__ __forceinline__ float fast_sqrt(float x) { return __builtin_amdgcn_sqrtf(x); }

// Ortho term for one sample. fp32 throughout EXCEPT detW (fp64): det has
// catastrophic cancellation (true value ~sigma1*sigma2*sigma3 << term
// magnitudes) and sigma_min feeds (sigma+eps)^-2 ~ 1e12 which dominates the
// loss.
__device__ __forceinline__ void sample_ortho(const float4 t0, const float4 t1,
                                             const float4 t2, double& ortho)
{
    float w00 = t0.x, w01 = t0.y, w02 = t0.z;
    float w10 = t1.x, w11 = t1.y, w12 = t1.z;
    float w20 = t2.x, w21 = t2.y, w22 = t2.z;

    // A = W^T W (fp32)
    float A00 = w00*w00 + w10*w10 + w20*w20;
    float A11 = w01*w01 + w11*w11 + w21*w21;
    float A22 = w02*w02 + w12*w12 + w22*w22;
    float A01 = w00*w01 + w10*w11 + w20*w21;
    float A02 = w00*w02 + w10*w12 + w20*w22;
    float A12 = w01*w02 + w11*w12 + w21*w22;

    float I1 = A00 + A11 + A22;
    float I2 = (A00*A11 - A01*A01) + (A00*A22 - A02*A02) + (A11*A22 - A12*A12);

    // det(W) in fp64 — the one cancellation-critical quantity.
    double dw = (double)w00 * ((double)w11 * (double)w22 - (double)w12 * (double)w21)
              - (double)w01 * ((double)w10 * (double)w22 - (double)w12 * (double)w20)
              + (double)w02 * ((double)w10 * (double)w21 - (double)w11 * (double)w20);
    float I3 = (float)(dw * dw);   // det(A) >= 0

    // Smallest eigenvalue: monotone fixed point lam <- I3 / q(lam),
    // q(lam) = lam^2 - I1*lam + I2. Converges from below; immediate for the
    // near-singular samples that dominate the loss.
    float lam = (I2 > 0.f) ? I3 * fast_rcp(I2) : 0.f;
    #pragma unroll
    for (int it = 0; it < 6; ++it) {
        float q = (lam - I1) * lam + I2;
        lam = (q > 0.f) ? I3 * fast_rcp(q) : lam;
    }
    if (lam < 0.f) lam = 0.f;

    // Remaining two eigenvalues from the deflated quadratic.
    float S = I1 - lam;
    float P = (lam - I1) * lam + I2;    // ~ lam1*lam2
    float disc = S * S - 4.f * P;
    disc = (disc > 0.f) ? fast_sqrt(disc) : 0.f;
    float l1 = 0.5f * (S + disc); if (l1 < 0.f) l1 = 0.f;
    float l2 = 0.5f * (S - disc); if (l2 < 0.f) l2 = 0.f;

    float s1 = fast_sqrt(l1)  + 1e-6f;
    float s2 = fast_sqrt(l2)  + 1e-6f;
    float s3 = fast_sqrt(lam) + 1e-6f;
    float q1 = s1 * s1, q2 = s2 * s2, q3 = s3 * s3;
    float inv = fast_rcp(q1 * q2 * q3);
    ortho += (double)((q1 + q2 + q3) + inv * (q2 * q3 + q1 * q3 + q1 * q2) - 6.f);
}

// Two-kernel structure (fusion measured strictly worse: the memset node +
// ticket epilogue cost more than the finalize dispatch they replaced).
// Direct strided loads — no LDS staging (every byte consumed exactly once;
// L1 merges the 48B-stride line touches). SPT=4 with a 2-stage register
// pipeline: load sample k+1 while computing sample k. This amortizes the
// per-block reduce epilogue + wave ramp/drain over 4x the bytes while
// keeping ~24 dwordx4 in flight per thread.
__global__ __launch_bounds__(256) void theta_loss_main(
    const float4* __restrict__ theta4,
    const float4* __restrict__ affine4,
    double* __restrict__ partial, int n)
{
    const int t = threadIdx.x;
    const int base = blockIdx.x * SPB + t;   // k-th sample: base + k*TPB
    double mse = 0.0, ortho = 0.0;

    float4 ct[3], ca[3];     // current sample's rows
    float4 nt_[3], na[3];    // next sample's rows (prefetch stage)

    // prologue: load sample 0
    {
        int s = base;
        if (s < n) {
            int j = 3 * s;
            ct[0] = theta4[j];  ct[1] = theta4[j + 1];  ct[2] = theta4[j + 2];
            ca[0] = affine4[j]; ca[1] = affine4[j + 1]; ca[2] = affine4[j + 2];
        } else {
            #pragma unroll
            for (int r = 0; r < 3; ++r) {
                ct[r] = make_float4(0.f, 0.f, 0.f, 0.f);
                ca[r] = make_float4(0.f, 0.f, 0.f, 0.f);
            }
        }
    }

    #pragma unroll
    for (int k = 0; k < SPT; ++k) {
        // prefetch sample k+1 (issued before the dependent compute of k)
        if (k + 1 < SPT) {
            int s = base + (k + 1) * TPB;
            if (s < n) {
                int j = 3 * s;
                nt_[0] = theta4[j];  nt_[1] = theta4[j + 1];  nt_[2] = theta4[j + 2];
                na[0] = affine4[j];  na[1] = affine4[j + 1];  na[2] = affine4[j + 2];
            } else {
                #pragma unroll
                for (int r = 0; r < 3; ++r) {
                    nt_[r] = make_float4(0.f, 0.f, 0.f, 0.f);
                    na[r] = make_float4(0.f, 0.f, 0.f, 0.f);
                }
            }
        }

        // compute sample k: MSE (fp32 within sample, widen once) + ortho
        {
            float m = 0.f;
            #pragma unroll
            for (int r = 0; r < 3; ++r) {
                float dx = ct[r].x - ca[r].x, dy = ct[r].y - ca[r].y;
                float dz = ct[r].z - ca[r].z, dw = ct[r].w - ca[r].w;
                m += dx * dx + dy * dy + dz * dz + dw * dw;
            }
            mse += (double)m;
            if (base + k * TPB < n)
                sample_ortho(ct[0], ct[1], ct[2], ortho);
        }

        // rotate pipeline (register renames after unroll, no moves emitted)
        if (k + 1 < SPT) {
            #pragma unroll
            for (int r = 0; r < 3; ++r) { ct[r] = nt_[r]; ca[r] = na[r]; }
        }
    }

    // ---- block reduction: wave64 shuffle -> LDS -> per-block partial ----
    #pragma unroll
    for (int off = 32; off > 0; off >>= 1) {
        ortho += __shfl_down(ortho, off);
        mse   += __shfl_down(mse, off);
    }
    __shared__ double so[4], sm[4];
    int lane = t & 63, wv = t >> 6;
    if (lane == 0) { so[wv] = ortho; sm[wv] = mse; }
    __syncthreads();
    if (t == 0) {
        partial[2 * blockIdx.x]     = so[0] + so[1] + so[2] + so[3];
        partial[2 * blockIdx.x + 1] = sm[0] + sm[1] + sm[2] + sm[3];
    }
}

__global__ __launch_bounds__(256) void finalize_out(
    const double* __restrict__ partial, float* __restrict__ out,
    int nblocks, int n)
{
    double O = 0.0, M = 0.0;
    for (int i = threadIdx.x; i < nblocks; i += 256) {
        O += partial[2 * i];
        M += partial[2 * i + 1];
    }
    #pragma unroll
    for (int off = 32; off > 0; off >>= 1) {
        O += __shfl_down(O, off);
        M += __shfl_down(M, off);
    }
    __shared__ double so[4], sm[4];
    int lane = threadIdx.x & 63, wv = threadIdx.x >> 6;
    if (lane == 0) { so[wv] = O; sm[wv] = M; }
    __syncthreads();
    if (threadIdx.x == 0) {
        double Ot = so[0] + so[1] + so[2] + so[3];
        double Mt = sm[0] + sm[1] + sm[2] + sm[3];
        out[0] = (float)(Ot / (double)n);
        out[1] = (float)(Mt / (12.0 * (double)n));
    }
}

extern "C" void kernel_launch(void* const* d_in, const int* in_sizes, int n_in,
                              void* d_out, int out_size, void* d_ws, size_t ws_size,
                              hipStream_t stream) {
    const float4* theta4  = (const float4*)d_in[0];
    const float4* affine4 = (const float4*)d_in[1];
    double* partial = (double*)d_ws;
    float* out = (float*)d_out;
    int n = in_sizes[0] / 12;           // samples of 3x4

    int blocks = (n + SPB - 1) / SPB;   // 1024 for n = 1M
    theta_loss_main<<<blocks, TPB, 0, stream>>>(theta4, affine4, partial, n);
    finalize_out<<<1, 256, 0, stream>>>(partial, out, blocks, n);
}

// Round 5
// 116.205 us; speedup vs baseline: 1.8137x; 1.0140x over previous
//
#include <hip/hip_runtime.h>
#include <math.h>

#define TPB 256          // threads per block
#define SPT 2            // samples per thread
#define SPB (TPB * SPT)  // samples per block

// HW-approx rcp/sqrt (v_rcp_f32 / v_sqrt_f32, ~1e-6 rel err). Error budget:
// sigma3 needs only ~0.4% rel accuracy once det is exact (fp64), and the
// final sv^-2 terms tolerate 1e-6 rel against the absmax-scaled threshold.
__device__ __forceinline__ float fast_rcp(float x)  { return __builtin_amdgcn_rcpf(x); }
__device__ __forceinline__ float fast_sqrt(float x) { return __builtin_amdgcn_sqrtf(x); }

// Ortho term for one sample. fp32 throughout EXCEPT detW (fp64): det has
// catastrophic cancellation (true value ~sigma1*sigma2*sigma3 << term
// magnitudes) and sigma_min feeds (sigma+eps)^-2 ~ 1e12 which dominates the
// loss.
__device__ __forceinline__ void sample_ortho(const float4 t0, const float4 t1,
                                             const float4 t2, double& ortho)
{
    float w00 = t0.x, w01 = t0.y, w02 = t0.z;
    float w10 = t1.x, w11 = t1.y, w12 = t1.z;
    float w20 = t2.x, w21 = t2.y, w22 = t2.z;

    // A = W^T W (fp32)
    float A00 = w00*w00 + w10*w10 + w20*w20;
    float A11 = w01*w01 + w11*w11 + w21*w21;
    float A22 = w02*w02 + w12*w12 + w22*w22;
    float A01 = w00*w01 + w10*w11 + w20*w21;
    float A02 = w00*w02 + w10*w12 + w20*w22;
    float A12 = w01*w02 + w11*w12 + w21*w22;

    float I1 = A00 + A11 + A22;
    float I2 = (A00*A11 - A01*A01) + (A00*A22 - A02*A02) + (A11*A22 - A12*A12);

    // det(W) in fp64 — the one cancellation-critical quantity.
    double dw = (double)w00 * ((double)w11 * (double)w22 - (double)w12 * (double)w21)
              - (double)w01 * ((double)w10 * (double)w22 - (double)w12 * (double)w20)
              + (double)w02 * ((double)w10 * (double)w21 - (double)w11 * (double)w20);
    float I3 = (float)(dw * dw);   // det(A) >= 0

    // Smallest eigenvalue: monotone fixed point lam <- I3 / q(lam),
    // q(lam) = lam^2 - I1*lam + I2. Converges from below; immediate for the
    // near-singular samples that dominate the loss.
    float lam = (I2 > 0.f) ? I3 * fast_rcp(I2) : 0.f;
    #pragma unroll
    for (int it = 0; it < 6; ++it) {
        float q = (lam - I1) * lam + I2;
        lam = (q > 0.f) ? I3 * fast_rcp(q) : lam;
    }
    if (lam < 0.f) lam = 0.f;

    // Remaining two eigenvalues from the deflated quadratic.
    float S = I1 - lam;
    float P = (lam - I1) * lam + I2;    // ~ lam1*lam2
    float disc = S * S - 4.f * P;
    disc = (disc > 0.f) ? fast_sqrt(disc) : 0.f;
    float l1 = 0.5f * (S + disc); if (l1 < 0.f) l1 = 0.f;
    float l2 = 0.5f * (S - disc); if (l2 < 0.f) l2 = 0.f;

    float s1 = fast_sqrt(l1)  + 1e-6f;
    float s2 = fast_sqrt(l2)  + 1e-6f;
    float s3 = fast_sqrt(lam) + 1e-6f;
    float q1 = s1 * s1, q2 = s2 * s2, q3 = s3 * s3;
    float inv = fast_rcp(q1 * q2 * q3);
    ortho += (double)((q1 + q2 + q3) + inv * (q2 * q3 + q1 * q3 + q1 * q2) - 6.f);
}

// Best-measured structure (115.7 us): two kernels, direct strided loads,
// SPT=2 with all 12 dwordx4 issued up-front. Measured-worse alternatives:
// LDS staging (118.0), fused+fence (210.8), fused+sc1 (127.8), SPT=4
// register pipeline (117.8). Timed region is dominated by 2x ~41us harness
// poison-fills at 82% HBM peak; main kernel sits near its HBM/L3 floor.
__global__ __launch_bounds__(256) void theta_loss_main(
    const float4* __restrict__ theta4,
    const float4* __restrict__ affine4,
    double* __restrict__ partial, int n)
{
    const int t = threadIdx.x;
    const int base = blockIdx.x * SPB + t;   // this thread's k-th sample: base + k*TPB
    double mse = 0.0, ortho = 0.0;

    float4 tv[SPT][3], av[SPT][3];
    #pragma unroll
    for (int k = 0; k < SPT; ++k) {
        int s = base + k * TPB;
        if (s < n) {
            int j = 3 * s;
            tv[k][0] = theta4[j];     tv[k][1] = theta4[j + 1];  tv[k][2] = theta4[j + 2];
            av[k][0] = affine4[j];    av[k][1] = affine4[j + 1]; av[k][2] = affine4[j + 2];
        } else {
            #pragma unroll
            for (int r = 0; r < 3; ++r) {
                tv[k][r] = make_float4(0.f, 0.f, 0.f, 0.f);
                av[k][r] = make_float4(0.f, 0.f, 0.f, 0.f);
            }
        }
    }

    // MSE: fp32 within a sample (<= 12 squared diffs, ~24 magnitude), widen once.
    #pragma unroll
    for (int k = 0; k < SPT; ++k) {
        float m = 0.f;
        #pragma unroll
        for (int r = 0; r < 3; ++r) {
            float dx = tv[k][r].x - av[k][r].x, dy = tv[k][r].y - av[k][r].y;
            float dz = tv[k][r].z - av[k][r].z, dw = tv[k][r].w - av[k][r].w;
            m += dx * dx + dy * dy + dz * dz + dw * dw;
        }
        mse += (double)m;
    }

    #pragma unroll
    for (int k = 0; k < SPT; ++k) {
        if (base + k * TPB < n)
            sample_ortho(tv[k][0], tv[k][1], tv[k][2], ortho);
    }

    // ---- block reduction: wave64 shuffle -> LDS -> per-block partial ----
    #pragma unroll
    for (int off = 32; off > 0; off >>= 1) {
        ortho += __shfl_down(ortho, off);
        mse   += __shfl_down(mse, off);
    }
    __shared__ double so[4], sm[4];
    int lane = t & 63, wv = t >> 6;
    if (lane == 0) { so[wv] = ortho; sm[wv] = mse; }
    __syncthreads();
    if (t == 0) {
        partial[2 * blockIdx.x]     = so[0] + so[1] + so[2] + so[3];
        partial[2 * blockIdx.x + 1] = sm[0] + sm[1] + sm[2] + sm[3];
    }
}

__global__ __launch_bounds__(256) void finalize_out(
    const double* __restrict__ partial, float* __restrict__ out,
    int nblocks, int n)
{
    double O = 0.0, M = 0.0;
    for (int i = threadIdx.x; i < nblocks; i += 256) {
        O += partial[2 * i];
        M += partial[2 * i + 1];
    }
    #pragma unroll
    for (int off = 32; off > 0; off >>= 1) {
        O += __shfl_down(O, off);
        M += __shfl_down(M, off);
    }
    __shared__ double so[4], sm[4];
    int lane = threadIdx.x & 63, wv = threadIdx.x >> 6;
    if (lane == 0) { so[wv] = O; sm[wv] = M; }
    __syncthreads();
    if (threadIdx.x == 0) {
        double Ot = so[0] + so[1] + so[2] + so[3];
        double Mt = sm[0] + sm[1] + sm[2] + sm[3];
        out[0] = (float)(Ot / (double)n);
        out[1] = (float)(Mt / (12.0 * (double)n));
    }
}

extern "C" void kernel_launch(void* const* d_in, const int* in_sizes, int n_in,
                              void* d_out, int out_size, void* d_ws, size_t ws_size,
                              hipStream_t stream) {
    const float4* theta4  = (const float4*)d_in[0];
    const float4* affine4 = (const float4*)d_in[1];
    double* partial = (double*)d_ws;
    float* out = (float*)d_out;
    int n = in_sizes[0] / 12;           // samples of 3x4

    int blocks = (n + SPB - 1) / SPB;   // 2048 for n = 1M
    theta_loss_main<<<blocks, TPB, 0, stream>>>(theta4, affine4, partial, n);
    finalize_out<<<1, 256, 0, stream>>>(partial, out, blocks, n);
}